// Round 5
// baseline (77.035 us; speedup 1.0000x reference)
//
#include <hip/hip_runtime.h>

#define N_REAL 12
#define BATCH  4
#define CH     3
#define HH     256
#define WW     256
#define KK     4
#define TY     16                 // output rows per tile (full 256-wide rows)
#define ROWS   19                 // TY + KK - 1 input rows
#define RSTR   264                // LDS row stride (dwords): 256 data + 8 zero pad
#define GUARD  4                  // zero quad before row 0 (serves gx=-1 at row 0)
#define PLANE  (ROWS * RSTR)      // 5016 dwords per channel
#define NTHR   512
#define HW     (HH * WW)
#define NSLOT  (ROWS * 66)        // 1254 float4 staging slots (66 quads incl. pad)

typedef float f32x4 __attribute__((ext_vector_type(4)));

__device__ __forceinline__ float sigmoidf(float x) {
    float e = __builtin_amdgcn_exp2f(x * -1.44269504088896340736f);
    return __builtin_amdgcn_rcpf(1.0f + e);
}

__global__ __launch_bounds__(NTHR, 6)   // 6 waves/EU -> 3 blocks/CU, VGPR cap 85
void reverb_fused(const float* __restrict__ states,
                  const float* __restrict__ weights,
                  const float* __restrict__ bias,
                  float*       __restrict__ out)
{
    __shared__ __align__(16) float sIn[GUARD + PLANE];   // 20.08 KB

    const int ty  = blockIdx.x;            // 0..15
    const int b   = blockIdx.y;            // batch
    const int v   = blockIdx.z;            // dest node
    const int tid = threadIdx.x;
    const int yb  = tid >> 6;              // 0..7  (2 output rows each)
    const int xb  = tid & 63;              // 0..63 (4 output cols each)
    const int gy0 = ty * TY;
    const int deg = (v == 0) ? 4 : 3;

    // ---- staging decomposition: 3 chunks of 512 slots, built once ----
    int goff[3], loff[3];
    #pragma unroll
    for (int k = 0; k < 3; ++k) {
        const int idx = tid + k * NTHR;
        const bool sv = idx < NSLOT;
        const int r   = idx / 66;
        const int c4  = idx - r * 66;
        const int gy  = gy0 + r - 1;       // SAME pad: lo=1, hi=2
        const bool gv = sv && (c4 < 64) && ((unsigned)gy < HH);
        goff[k] = gv ? (gy * WW + 4 * c4) : -1;
        loff[k] = sv ? (GUARD + r * RSTR + 4 * c4) : -1;
    }

    if (tid == 0) *(f32x4*)sIn = (f32x4){0.f, 0.f, 0.f, 0.f};  // guard quad

    float acc[CH][2][4];
    #pragma unroll
    for (int co = 0; co < CH; ++co)
        #pragma unroll
        for (int yy = 0; yy < 2; ++yy)
            #pragma unroll
            for (int p = 0; p < 4; ++p) acc[co][yy][p] = 0.0f;
    float bsum[CH] = {0.f, 0.f, 0.f};

    // ---- prefetch (edge 0, channel 0) ----
    f32x4 pre[3];
    {
        const int u0 = (v + 11) % 12;
        const float* src0 = states + (size_t)(u0 * BATCH + b) * CH * HW;
        #pragma unroll
        for (int k = 0; k < 3; ++k)
            pre[k] = (goff[k] >= 0) ? *(const f32x4*)(src0 + goff[k])
                                    : (f32x4){0.f, 0.f, 0.f, 0.f};
    }

    for (int ei = 0; ei < deg; ++ei) {
        const int uc = (ei == 3) ? 12 : ((v + 11 - ei) % 12);
        const int e  = (ei == 3) ? 36 : (uc * 3 + ei);
        const float* srcE = states + (size_t)(uc * BATCH + b) * CH * HW;

        const float* nextSrc = nullptr;    // next edge's channel-0 base
        if (ei + 1 < deg) {
            const int un = (ei + 1 == 3) ? 12 : ((v + 10 - ei) % 12);
            nextSrc = states + (size_t)(un * BATCH + b) * CH * HW;
        }

        bsum[0] += bias[e * CH + 0];
        bsum[1] += bias[e * CH + 1];
        bsum[2] += bias[e * CH + 2];
        const float* __restrict__ wbase = weights + e * (CH * CH * KK * KK);

        #pragma unroll
        for (int ci = 0; ci < CH; ++ci) {
            __syncthreads();               // previous phase's readers done
            #pragma unroll
            for (int k = 0; k < 3; ++k) {
                if (loff[k] >= 0) {
                    f32x4 t = (f32x4){0.f, 0.f, 0.f, 0.f};
                    if (goff[k] >= 0) {
                        t.x = sigmoidf(pre[k].x);
                        t.y = sigmoidf(pre[k].y);
                        t.z = sigmoidf(pre[k].z);
                        t.w = sigmoidf(pre[k].w);
                    }
                    *(f32x4*)(sIn + loff[k]) = t;
                }
            }
            __syncthreads();               // channel tile ready

            // ---- prefetch next phase under this phase's compute ----
            const float* nsrc = (ci < 2) ? (srcE + (size_t)(ci + 1) * HW)
                                         : nextSrc;
            if (nsrc) {
                #pragma unroll
                for (int k = 0; k < 3; ++k)
                    pre[k] = (goff[k] >= 0) ? *(const f32x4*)(nsrc + goff[k])
                                            : (f32x4){0.f, 0.f, 0.f, 0.f};
            }

            // ---- compute channel ci ----
            #pragma unroll
            for (int lr = 0; lr < 5; ++lr) {
                const float* rp = sIn + GUARD + (2 * yb + lr) * RSTR + 4 * xb;
                const f32x4 A  = *(const f32x4*)(rp - 4);   // need A.w (gx-1)
                const f32x4 Bq = *(const f32x4*)(rp);
                const f32x4 Cq = *(const f32x4*)(rp + 4);   // need x,y
                const float vv[7] = {A.w, Bq.x, Bq.y, Bq.z, Bq.w, Cq.x, Cq.y};
                #pragma unroll
                for (int yy = 0; yy < 2; ++yy) {
                    const int ky = lr - yy;
                    if (ky < 0 || ky > 3) continue;
                    #pragma unroll
                    for (int co = 0; co < CH; ++co) {
                        const f32x4 wv =
                            *(const f32x4*)(wbase + ((co * CH + ci) * KK + ky) * KK);
                        #pragma unroll
                        for (int p = 0; p < 4; ++p) {
                            acc[co][yy][p] = fmaf(wv.x, vv[p + 0], acc[co][yy][p]);
                            acc[co][yy][p] = fmaf(wv.y, vv[p + 1], acc[co][yy][p]);
                            acc[co][yy][p] = fmaf(wv.z, vv[p + 2], acc[co][yy][p]);
                            acc[co][yy][p] = fmaf(wv.w, vv[p + 3], acc[co][yy][p]);
                        }
                    }
                }
            }
        }
    }

    const float inv = 1.0f / (float)deg;
    const size_t obase = (size_t)(v * BATCH + b) * CH * HW;
    #pragma unroll
    for (int co = 0; co < CH; ++co) {
        #pragma unroll
        for (int yy = 0; yy < 2; ++yy) {
            const int oy = gy0 + 2 * yb + yy;
            f32x4 o;
            o.x = (acc[co][yy][0] + bsum[co]) * inv;
            o.y = (acc[co][yy][1] + bsum[co]) * inv;
            o.z = (acc[co][yy][2] + bsum[co]) * inv;
            o.w = (acc[co][yy][3] + bsum[co]) * inv;
            __builtin_nontemporal_store(o,
                (f32x4*)&out[obase + (size_t)co * HW + (size_t)oy * WW + 4 * xb]);
        }
    }
}

extern "C" void kernel_launch(void* const* d_in, const int* in_sizes, int n_in,
                              void* d_out, int out_size, void* d_ws, size_t ws_size,
                              hipStream_t stream)
{
    const float* states  = (const float*)d_in[0];
    const float* weights = (const float*)d_in[1];
    const float* bias    = (const float*)d_in[2];
    float*       out     = (float*)d_out;

    dim3 grid(HH / TY, BATCH, N_REAL);     // 16 x 4 x 12 = 768 = exactly 3 blocks/CU
    reverb_fused<<<grid, NTHR, 0, stream>>>(states, weights, bias, out);
}

// Round 6
// 59.127 us; speedup vs baseline: 1.3029x; 1.3029x over previous
//
#include <hip/hip_runtime.h>

#define N_REAL 12
#define BATCH  4
#define CH     3
#define HH     256
#define WW     256
#define KK     4
#define TY     8                  // output rows per tile (full 256-wide rows)
#define ROWSR  11                 // TY + KK - 1 input rows
#define RSTR   264                // LDS row stride (dwords): 256 data + 8 zero pad
#define NTHR   256
#define HW     (HH * WW)
#define NPAD   (4 + ROWSR * 8)    // guard quad + per-row pad dwords to zero once

typedef float f32x4 __attribute__((ext_vector_type(4)));

__device__ __forceinline__ float sigmoidf(float x) {
    float e = __builtin_amdgcn_exp2f(x * -1.44269504088896340736f);
    return __builtin_amdgcn_rcpf(1.0f + e);
}

__global__ __launch_bounds__(NTHR, 6)   // 6 waves/EU -> 6 blocks/CU, VGPR cap 85
void reverb_fused(const float* __restrict__ states,
                  const float* __restrict__ weights,
                  const float* __restrict__ bias,
                  float*       __restrict__ out)
{
    // guard(4) + 11 rows * 264; rows start 16B-aligned; pads stay zero forever.
    __shared__ __align__(16) float S[4 + ROWSR * RSTR];   // 11.6 KB

    const int ty  = blockIdx.x;            // 0..31
    const int b   = blockIdx.y;            // batch
    const int v   = blockIdx.z;            // dest node
    const int tid = threadIdx.x;
    const int w   = tid >> 6;              // wave 0..3 == output row-pair owner
    const int ln  = tid & 63;              // lane == output col-quad
    const int gy0 = ty * TY;
    const int deg = (v == 0) ? 4 : 3;

    // ---- one-time zeroing of guard + row pads (never overwritten) ----
    if (tid < NPAD) {
        if (tid < 4) S[tid] = 0.0f;
        else {
            const int i = tid - 4;
            S[4 + (i >> 3) * RSTR + 256 + (i & 7)] = 0.0f;
        }
    }

    float acc[CH][2][4];
    #pragma unroll
    for (int co = 0; co < CH; ++co)
        #pragma unroll
        for (int yy = 0; yy < 2; ++yy)
            #pragma unroll
            for (int p = 0; p < 4; ++p) acc[co][yy][p] = 0.0f;
    float bsum[CH] = {0.f, 0.f, 0.f};

    for (int ei = 0; ei < deg; ++ei) {
        const int uc = (ei == 3) ? 12 : ((v + 11 - ei) % 12);
        const int e  = (ei == 3) ? 36 : (uc * 3 + ei);
        const float* __restrict__ srcE = states + (size_t)(uc * BATCH + b) * CH * HW;
        const float* __restrict__ wbase = weights + e * (CH * CH * KK * KK);
        bsum[0] += bias[e * CH + 0];
        bsum[1] += bias[e * CH + 1];
        bsum[2] += bias[e * CH + 2];

        #pragma unroll
        for (int ci = 0; ci < CH; ++ci) {
            const float* __restrict__ srcC = srcE + (size_t)ci * HW;

            __syncthreads();               // previous phase's readers done

            // ---- stage: wave w owns rows w, w+4, w+8 (clamped loads, OOB->0) ----
            #pragma unroll
            for (int k = 0; k < 3; ++k) {
                const int r = w + 4 * k;
                if (r < ROWSR) {           // wave-uniform (only w=3,k=2 skips)
                    const int gy  = gy0 + r - 1;          // SAME pad lo=1
                    const int gyc = gy < 0 ? 0 : (gy > HH - 1 ? HH - 1 : gy);
                    const f32x4 q = *(const f32x4*)(srcC + gyc * WW + 4 * ln);
                    f32x4 t;
                    if ((unsigned)gy < HH) {
                        t.x = sigmoidf(q.x); t.y = sigmoidf(q.y);
                        t.z = sigmoidf(q.z); t.w = sigmoidf(q.w);
                    } else {
                        t = (f32x4){0.f, 0.f, 0.f, 0.f};
                    }
                    *(f32x4*)(S + 4 + r * RSTR + 4 * ln) = t;
                }
            }
            __syncthreads();               // channel tile ready

            // ---- compute: 5 LDS rows -> 2 output rows, 3 co ----
            #pragma unroll
            for (int lr = 0; lr < 5; ++lr) {
                const float* rp = S + 4 + (2 * w + lr) * RSTR + 4 * ln;
                const f32x4 A  = *(const f32x4*)(rp - 4);   // A.w = x-1 (guard/pad)
                const f32x4 Bq = *(const f32x4*)(rp);
                const f32x4 Cq = *(const f32x4*)(rp + 4);   // x+4, x+5 (pad at edge)
                const float vv[7] = {A.w, Bq.x, Bq.y, Bq.z, Bq.w, Cq.x, Cq.y};
                #pragma unroll
                for (int yy = 0; yy < 2; ++yy) {
                    const int ky = lr - yy;
                    if (ky < 0 || ky > 3) continue;
                    #pragma unroll
                    for (int co = 0; co < CH; ++co) {
                        const f32x4 wv =
                            *(const f32x4*)(wbase + ((co * CH + ci) * KK + ky) * KK);
                        #pragma unroll
                        for (int p = 0; p < 4; ++p) {
                            acc[co][yy][p] = fmaf(wv.x, vv[p + 0], acc[co][yy][p]);
                            acc[co][yy][p] = fmaf(wv.y, vv[p + 1], acc[co][yy][p]);
                            acc[co][yy][p] = fmaf(wv.z, vv[p + 2], acc[co][yy][p]);
                            acc[co][yy][p] = fmaf(wv.w, vv[p + 3], acc[co][yy][p]);
                        }
                    }
                }
            }
        }
    }

    const float inv = 1.0f / (float)deg;
    const size_t obase = (size_t)(v * BATCH + b) * CH * HW;
    #pragma unroll
    for (int co = 0; co < CH; ++co) {
        #pragma unroll
        for (int yy = 0; yy < 2; ++yy) {
            const int oy = gy0 + 2 * w + yy;
            f32x4 o;
            o.x = (acc[co][yy][0] + bsum[co]) * inv;
            o.y = (acc[co][yy][1] + bsum[co]) * inv;
            o.z = (acc[co][yy][2] + bsum[co]) * inv;
            o.w = (acc[co][yy][3] + bsum[co]) * inv;
            __builtin_nontemporal_store(o,
                (f32x4*)&out[obase + (size_t)co * HW + (size_t)oy * WW + 4 * ln]);
        }
    }
}

extern "C" void kernel_launch(void* const* d_in, const int* in_sizes, int n_in,
                              void* d_out, int out_size, void* d_ws, size_t ws_size,
                              hipStream_t stream)
{
    const float* states  = (const float*)d_in[0];
    const float* weights = (const float*)d_in[1];
    const float* bias    = (const float*)d_in[2];
    float*       out     = (float*)d_out;

    dim3 grid(HH / TY, BATCH, N_REAL);     // 32 x 4 x 12 = 1536 = 6 blocks/CU resident
    reverb_fused<<<grid, NTHR, 0, stream>>>(states, weights, bias, out);
}